// Round 4
// baseline (317.715 us; speedup 1.0000x reference)
//
#include <hip/hip_runtime.h>

#define NODES 100000
#define EDGES 3200000
#define D 128
#define NBUCKET ((NODES + 255) / 256)    // 391 dst-buckets of 256 nodes
#define NBUCKP 392                       // padded even for pairwise scan
#define CH 4096                          // edges per binning block
#define NB_BIN ((EDGES + CH - 1) / CH)   // 782 binning blocks
#define GEMM_NB ((NODES + 63) / 64)      // 1563 gemm blocks
#define CAP 10240                        // static per-bucket slot capacity (actual max ~8550)

typedef unsigned short us8 __attribute__((ext_vector_type(8)));
typedef _Float16 half8 __attribute__((ext_vector_type(8)));
typedef _Float16 h2 __attribute__((ext_vector_type(2)));
typedef float f32x4 __attribute__((ext_vector_type(4)));

__device__ __forceinline__ unsigned short f32_to_f16_bits(float f) {
    return __builtin_bit_cast(unsigned short, (_Float16)f);
}
__device__ __forceinline__ h2 uh2(unsigned u) {
    return __builtin_bit_cast(h2, u);
}

// ---------------- fused: bin_pass1 (blocks 0..781) || gemm (782..2344) ------
// gemm and pass1 are data-independent; fusing removes their serialization.
// 40-KB LDS union: pass1 {sed 32768 | hist 1568 | basel | lcur | gbase | wsum},
// gemm {wl 32768}. w converted fp32->fp16 inline (wprep kernel eliminated).
__global__ __launch_bounds__(256) void fusedA(const float* __restrict__ x,
                                              const float* __restrict__ w,
                                              const int* __restrict__ esrc,
                                              const int* __restrict__ edst,
                                              const float* __restrict__ eval,
                                              int* __restrict__ bcur,
                                              int2* __restrict__ tmp,
                                              unsigned short* __restrict__ hb) {
    __shared__ __align__(16) char smem[39072];
    const int tid = threadIdx.x;

    if (blockIdx.x < NB_BIN) {
        // ---------------- bin_pass1: in-LDS counting sort, coalesced writeout
        int2* sed   = (int2*)smem;                 // 32768 B
        int*  hist  = (int*)(smem + 32768);        // 1568 B
        int*  basel = (int*)(smem + 34336);
        int*  lcur  = (int*)(smem + 35904);
        int*  gbase = (int*)(smem + 37472);
        int*  wsum  = (int*)(smem + 39040);        // 16 B
        const long e0 = (long)blockIdx.x * CH;
        const int n = (int)((EDGES - e0 < CH) ? (EDGES - e0) : CH);

        for (int bk = tid; bk < NBUCKP; bk += 256) { hist[bk] = 0; lcur[bk] = 0; }
        __syncthreads();
        for (int i = tid; i < n; i += 256)
            atomicAdd(&hist[edst[e0 + i] >> 8], 1);
        __syncthreads();

        // pairwise exclusive scan of 392 bins: thread t owns bins 2t, 2t+1
        int h0 = 0, h1 = 0;
        if (tid < 196) { h0 = hist[2 * tid]; h1 = hist[2 * tid + 1]; }
        int s = h0 + h1;
        int lane = tid & 63, wid = tid >> 6;
        int sc = s;
#pragma unroll
        for (int off = 1; off < 64; off <<= 1) {
            int t = __shfl_up(sc, off, 64);
            if (lane >= off) sc += t;
        }
        if (lane == 63) wsum[wid] = sc;
        __syncthreads();
        int wb = 0;
        for (int w2 = 0; w2 < wid; w2++) wb += wsum[w2];
        int excl = wb + sc - s;
        if (tid < 196) { basel[2 * tid] = excl; basel[2 * tid + 1] = excl + h0; }
        // reserve global bucket ranges (bcur holds per-bucket COUNTS, zeroed by memset)
        for (int bk = tid; bk < NBUCKET; bk += 256) {
            int c = hist[bk];
            if (c > 0) gbase[bk] = bk * CAP + atomicAdd(&bcur[bk], c);
        }
        __syncthreads();

        // scatter into LDS, sorted by bucket
        // pk = (fp16_bits(val) << 17) | src   (val in [0,1) -> bits < 0x3C00 < 2^15)
        for (int i = tid; i < n; i += 256) {
            long e = e0 + i;
            int dst = edst[e];
            unsigned hv = (unsigned)f32_to_f16_bits(eval[e]);
            unsigned pk = (hv << 17) | (unsigned)esrc[e];
            int bk = dst >> 8;
            int lp = basel[bk] + atomicAdd(&lcur[bk], 1);
            sed[lp] = make_int2((int)pk, dst);
        }
        __syncthreads();

        // coalesced write-out: consecutive i -> consecutive global within runs
        for (int i = tid; i < n; i += 256) {
            int2 t = sed[i];
            int bk = t.y >> 8;
            tmp[gbase[bk] + (i - basel[bk])] = t;
        }
    } else {
        // ---------------- gemm: h = fp16(x) @ fp16(w), w converted inline ---
        unsigned short* wl = (unsigned short*)smem;   // 32768 B
        // wl[((ct*4+c)*64+l)*8+j] = f16(w[(32c+(l>>4)*8+j)][16ct+(l&15)])
        for (int i = tid; i < 16384; i += 256) {
            int j  = i & 7;
            int l  = (i >> 3) & 63;
            int c  = (i >> 9) & 3;
            int ct = i >> 11;
            int k   = 32 * c + ((l >> 4) << 3) + j;
            int col = (ct << 4) + (l & 15);
            wl[i] = f32_to_f16_bits(w[k * D + col]);
        }
        __syncthreads();

        const int wave = tid >> 6, lane = tid & 63;
        const long r0 = ((long)(blockIdx.x - NB_BIN) * 4 + wave) * 16;
        if (r0 >= NODES) return;
        const int m = lane & 15, q = lane >> 4;
        const float* xr = x + (r0 + m) * D;

        f32x4 acc[8];
#pragma unroll
        for (int ct = 0; ct < 8; ct++) acc[ct] = (f32x4){0.f, 0.f, 0.f, 0.f};

#pragma unroll
        for (int c = 0; c < 4; c++) {
            const int k0 = 32 * c + 8 * q;
            float4 xa = *(const float4*)(xr + k0);
            float4 xb = *(const float4*)(xr + k0 + 4);
            half8 a;
            a[0] = (_Float16)xa.x;
            a[1] = (_Float16)xa.y;
            a[2] = (_Float16)xa.z;
            a[3] = (_Float16)xa.w;
            a[4] = (_Float16)xb.x;
            a[5] = (_Float16)xb.y;
            a[6] = (_Float16)xb.z;
            a[7] = (_Float16)xb.w;
#pragma unroll
            for (int ct = 0; ct < 8; ct++) {
                half8 bfr = *(const half8*)&wl[(((ct << 2) + c) * 64 + lane) * 8];
                acc[ct] = __builtin_amdgcn_mfma_f32_16x16x32_f16(a, bfr, acc[ct], 0, 0, 0);
            }
        }

        // C/D: col = lane&15, row = (lane>>4)*4 + reg
#pragma unroll
        for (int ct = 0; ct < 8; ct++) {
#pragma unroll
            for (int r = 0; r < 4; r++) {
                int row = q * 4 + r;
                hb[(r0 + row) * D + ct * 16 + m] = f32_to_f16_bits(acc[ct][r]);
            }
        }
    }
}

// ---------------- pass 2: LDS-staged bucket -> per-node CSR + in-place epack
// epack ALIASES tmp. rpd[node] = ((2*b*CAP + excl) << 8) | degree.
__global__ __launch_bounds__(256) void bin_pass2(const int* __restrict__ bcur,
                                                 const int2* __restrict__ tmp,
                                                 int* __restrict__ rpd,
                                                 unsigned* __restrict__ epk) {
    __shared__ unsigned spk[CAP];        // 40 KB
    __shared__ unsigned char sd8[CAP];   // 10 KB
    __shared__ int cnt[256];
    __shared__ int pos[256];
    __shared__ int wsum[4];
    const int b = blockIdx.x;
    const int tid = threadIdx.x;
    const int beg = b * CAP;
    const int n = bcur[b];               // bcur now holds per-bucket counts

    cnt[tid] = 0;
    __syncthreads();
    for (int i = tid; i < n; i += 256) {
        int2 t = tmp[beg + i];
        spk[i] = (unsigned)t.x;
        int d8 = t.y & 255;
        sd8[i] = (unsigned char)d8;
        atomicAdd(&cnt[d8], 1);
    }
    __syncthreads();

    int v = cnt[tid];
    int lane = tid & 63, wid = tid >> 6;
    int s = v;
#pragma unroll
    for (int off = 1; off < 64; off <<= 1) {
        int t = __shfl_up(s, off, 64);
        if (lane >= off) s += t;
    }
    if (lane == 63) wsum[wid] = s;
    __syncthreads();
    int wbase = 0;
    for (int w = 0; w < wid; w++) wbase += wsum[w];
    int excl = wbase + s - v;
    pos[tid] = excl;
    int node = (b << 8) + tid;
    if (node < NODES) rpd[node] = (((beg << 1) + excl) << 8) | v;
    __syncthreads();

    for (int i = tid; i < n; i += 256) {
        int p = atomicAdd(&pos[sd8[i]], 1);
        epk[(beg << 1) + p] = spk[i];
    }
}

// ---------------- aggregation: 1 node/wave, 4 subs x 16 lanes, fp16 pk_fma --
// Per edge: 16 lanes x uint4 = full 256-B fp16 row, consumed by v_pk_fma_f16
// with zero unpack instructions. MSHR-concurrency-bound (~3.9 TB/s random
// fetch): per-CU line-miss rate ~1/23 cyc matches 32 MSHRs / ~640 cyc latency.
__global__ __launch_bounds__(256) void aggregate(const int* __restrict__ rpd,
                                                 const unsigned* __restrict__ epack,
                                                 const unsigned short* __restrict__ hb,
                                                 const float* __restrict__ bias,
                                                 float* __restrict__ out) {
    const int lane = threadIdx.x & 63;
    const int node = blockIdx.x * 4 + (threadIdx.x >> 6);
    if (node >= NODES) return;
    const int sub = lane >> 4;       // 4 edge slots per wave
    const int li  = lane & 15;       // 16 lanes x 8 ch = 128 channels
    const int v = rpd[node];
    const int beg = (int)(((unsigned)v) >> 8);
    const int end = beg + (v & 255);
    const unsigned short* hp = hb + li * 8;

    h2 aA0 = (h2)0, aA1 = (h2)0, aA2 = (h2)0, aA3 = (h2)0;
    h2 aB0 = (h2)0, aB1 = (h2)0, aB2 = (h2)0, aB3 = (h2)0;

    for (int e0 = beg + sub; e0 < end; e0 += 16) {
        int i0 = e0, i1 = e0 + 4, i2 = e0 + 8, i3 = e0 + 12;
        unsigned p0 = epack[i0];                       // i0 < end guaranteed
        unsigned p1 = (i1 < end) ? epack[i1] : 0u;     // pk=0 -> val=0, src=0
        unsigned p2 = (i2 < end) ? epack[i2] : 0u;
        unsigned p3 = (i3 < end) ? epack[i3] : 0u;

        unsigned s0 = p0 & 0x1FFFFu, s1 = p1 & 0x1FFFFu;
        unsigned s2 = p2 & 0x1FFFFu, s3 = p3 & 0x1FFFFu;
        unsigned v0 = p0 >> 17, v1 = p1 >> 17, v2 = p2 >> 17, v3 = p3 >> 17;

        uint4 r0 = *(const uint4*)(hp + (size_t)s0 * D);
        uint4 r1 = *(const uint4*)(hp + (size_t)s1 * D);
        uint4 r2 = *(const uint4*)(hp + (size_t)s2 * D);
        uint4 r3 = *(const uint4*)(hp + (size_t)s3 * D);

        h2 w0 = uh2(v0 | (v0 << 16));
        h2 w1 = uh2(v1 | (v1 << 16));
        h2 w2 = uh2(v2 | (v2 << 16));
        h2 w3 = uh2(v3 | (v3 << 16));

        aA0 = uh2(r0.x) * w0 + aA0;
        aA1 = uh2(r0.y) * w0 + aA1;
        aA2 = uh2(r0.z) * w0 + aA2;
        aA3 = uh2(r0.w) * w0 + aA3;
        aB0 = uh2(r1.x) * w1 + aB0;
        aB1 = uh2(r1.y) * w1 + aB1;
        aB2 = uh2(r1.z) * w1 + aB2;
        aB3 = uh2(r1.w) * w1 + aB3;
        aA0 = uh2(r2.x) * w2 + aA0;
        aA1 = uh2(r2.y) * w2 + aA1;
        aA2 = uh2(r2.z) * w2 + aA2;
        aA3 = uh2(r2.w) * w2 + aA3;
        aB0 = uh2(r3.x) * w3 + aB0;
        aB1 = uh2(r3.y) * w3 + aB1;
        aB2 = uh2(r3.z) * w3 + aB2;
        aB3 = uh2(r3.w) * w3 + aB3;
    }

    // merge acc sets in fp16 (few-ulp partials), then f32 for the reduce
    h2 m0 = aA0 + aB0, m1 = aA1 + aB1, m2 = aA2 + aB2, m3 = aA3 + aB3;
    float r[8];
    r[0] = (float)m0[0]; r[1] = (float)m0[1];
    r[2] = (float)m1[0]; r[3] = (float)m1[1];
    r[4] = (float)m2[0]; r[5] = (float)m2[1];
    r[6] = (float)m3[0]; r[7] = (float)m3[1];
#pragma unroll
    for (int k = 0; k < 8; k++) {
        r[k] += __shfl_xor(r[k], 16, 64);
        r[k] += __shfl_xor(r[k], 32, 64);
    }

    if (sub == 0) {
        const float* bp = bias + li * 8;
        float4 b0 = *(const float4*)bp;
        float4 b1 = *(const float4*)(bp + 4);
        float4 o0, o1;
        o0.x = fmaxf(r[0] + b0.x, 0.f);
        o0.y = fmaxf(r[1] + b0.y, 0.f);
        o0.z = fmaxf(r[2] + b0.z, 0.f);
        o0.w = fmaxf(r[3] + b0.w, 0.f);
        o1.x = fmaxf(r[4] + b1.x, 0.f);
        o1.y = fmaxf(r[5] + b1.y, 0.f);
        o1.z = fmaxf(r[6] + b1.z, 0.f);
        o1.w = fmaxf(r[7] + b1.w, 0.f);
        float* op = out + (size_t)node * D + li * 8;
        *(float4*)op = o0;
        *(float4*)(op + 4) = o1;
    }
}

extern "C" void kernel_launch(void* const* d_in, const int* in_sizes, int n_in,
                              void* d_out, int out_size, void* d_ws, size_t ws_size,
                              hipStream_t stream) {
    const float* x    = (const float*)d_in[0];
    const int*   esrc = (const int*)  d_in[1];
    const int*   edst = (const int*)  d_in[2];
    const float* eval = (const float*)d_in[3];
    const float* w    = (const float*)d_in[4];
    const float* b    = (const float*)d_in[5];
    float* out = (float*)d_out;

    // workspace layout (bytes), total 58,032,896
    char* ws = (char*)d_ws;
    const size_t OFF_H    = 0;                       // 25,600,000 (fp16 h)
    const size_t OFF_RPD  = 25600000;                // 400,000 -> pad 400,128
    const size_t OFF_BCUR = OFF_RPD  + 400128;       // 2,048
    const size_t OFF_TMP  = OFF_BCUR + 2048;         // 391*CAP*8 = 32,030,720 (epack aliases)

    unsigned short* hb   = (unsigned short*)(ws + OFF_H);
    int*            rpd  = (int*)           (ws + OFF_RPD);
    int*            bcur = (int*)           (ws + OFF_BCUR);
    int2*           tmp  = (int2*)          (ws + OFF_TMP);
    unsigned*       epk  = (unsigned*)      (ws + OFF_TMP);   // in-place alias

    hipMemsetAsync(bcur, 0, NBUCKET * sizeof(int), stream);
    fusedA<<<NB_BIN + GEMM_NB, 256, 0, stream>>>(x, w, esrc, edst, eval, bcur, tmp, hb);
    bin_pass2<<<NBUCKET, 256, 0, stream>>>(bcur, tmp, rpd, epk);
    aggregate<<<(NODES + 3) / 4, 256, 0, stream>>>(rpd, epk, hb, b, out);
}